// Round 17
// baseline (251.871 us; speedup 1.0000x reference)
//
#include <hip/hip_runtime.h>
#include <math.h>

#define B 64
#define S 2048
#define D 512
#define H 512

#define WSC 128  // s-rows per k_wsum chunk
#define LDA 40   // A-tile padded row stride in halfs (80 B, 16B-aligned, 2-way banks)

typedef _Float16 f16x8 __attribute__((ext_vector_type(8)));
typedef __fp16 fp16x2 __attribute__((ext_vector_type(2)));
typedef float f32x4 __attribute__((ext_vector_type(4)));

// ws layout: [0,512K) WcP packed fp16; [512K,512K+2M) wsum partials f32 [16][B][D];
//            [512K+4M, +256B) mask partial counts int[64]
#define WS_PART_OFF (512 * 1024)
#define WS_CNT_OFF  (512 * 1024 + 4 * 1024 * 1024)

// NOTE (m104/m108): LDS dest must be the WAVE-UNIFORM segment base; HW writes
// lane l at base + l*16. Global src is per-lane.
#define GLOAD16(g, l)                                                          \
    __builtin_amdgcn_global_load_lds(                                          \
        (const __attribute__((address_space(1))) uint32_t*)(g),                \
        (__attribute__((address_space(3))) uint32_t*)(l), 16, 0, 0)

// ---------------------------------------------------------------------------
// K_prep: fused {pack Wc -> fp16 frag order} + {input linear} + {mask counts}
// ---------------------------------------------------------------------------
__global__ __launch_bounds__(256) void k_prep(
        const float* __restrict__ Wc, _Float16* __restrict__ wsB,
        const float* __restrict__ input, const float* __restrict__ W_in,
        const float* __restrict__ b_in, float* __restrict__ out_inp,
        const int* __restrict__ mask, int* __restrict__ cntArr) {
    const int bid = blockIdx.x;
    const int tid = threadIdx.x;

    if (bid < 128) {
        const int slot = bid * 256 + tid;   // 0..32767
        const int st   = slot >> 11;
        const int rem  = slot & 2047;
        const int hg   = rem >> 6;
        const int lane = rem & 63;
        const int h  = hg * 16 + (lane & 15);
        const int k0 = st * 32 + (lane >> 4) * 8;
        const float* src = Wc + (size_t)h * D + k0;
        float4 f0 = *(const float4*)src;
        float4 f1 = *(const float4*)(src + 4);
        f16x8 v;
        v[0] = (_Float16)f0.x; v[1] = (_Float16)f0.y;
        v[2] = (_Float16)f0.z; v[3] = (_Float16)f0.w;
        v[4] = (_Float16)f1.x; v[5] = (_Float16)f1.y;
        v[6] = (_Float16)f1.z; v[7] = (_Float16)f1.w;
        *(f16x8*)(wsB + (size_t)slot * 8) = v;
    } else if (bid < 192) {
        const int b = bid - 128;
        __shared__ float xrow[D];
        for (int d = tid; d < D; d += 256) xrow[d] = input[(size_t)b * D + d];
        __syncthreads();
        for (int h = tid; h < H; h += 256) {
            const float* w = W_in + (size_t)h * D;
            float acc = 0.f;
            #pragma unroll 4
            for (int d = 0; d < D; d += 4) {
                float4 wv = *(const float4*)(w + d);
                acc += wv.x * xrow[d] + wv.y * xrow[d + 1] + wv.z * xrow[d + 2] + wv.w * xrow[d + 3];
            }
            out_inp[(size_t)b * H + h] = acc + b_in[h];
        }
    } else {
        const int i0 = (bid - 192) * 2048;
        int local = 0;
        #pragma unroll
        for (int it = 0; it < 8; ++it)
            local += (mask[i0 + it * 256 + tid] != 0) ? 1 : 0;
        #pragma unroll
        for (int off = 32; off; off >>= 1) local += __shfl_down(local, off, 64);
        __shared__ int ired[4];
        if ((tid & 63) == 0) ired[tid >> 6] = local;
        __syncthreads();
        if (tid == 0) cntArr[bid - 192] = ired[0] + ired[1] + ired[2] + ired[3];
    }
}

// ---------------------------------------------------------------------------
// K2 (MFMA): fused ctx-GEMM + tanh + V-reduce, gload_lds-staged B.
//   Grid 4096: hb = bid&1 (h-half), stile = bid>>1 -> b = stile>>5 (0..63),
//   s0 = (stile&31)*64.  [r15/r16 crash: decode used >>4/&15 -> b up to 127,
//   out-of-bounds ctx reads]
//   B: fp16 frag-order panels DMA'd to LDS via global_load_lds, dbuf; each
//   wave stages its 4 hg-slices. A: reg-staged cvt, LDA=40, dbuf. One
//   barrier per K=32 step. Epilogue atomicAdds over the 2 h-halves.
// ---------------------------------------------------------------------------
__global__ __launch_bounds__(256) void k_energy(
        const float* __restrict__ ctx,
        const _Float16* __restrict__ WcP,
        const float* __restrict__ bc,
        const float* __restrict__ inp,
        const float* __restrict__ V,
        float* __restrict__ att) {
    __shared__ alignas(16) _Float16 Alds[2][64 * LDA];   // 2 x 5 KB
    __shared__ alignas(16) _Float16 Blds[2][8192];       // 2 x 16 KB
    __shared__ float red[4][64];

    const int tid = threadIdx.x;
    const int hb    = blockIdx.x & 1;           // h-half: 0 or 1
    const int stile = blockIdx.x >> 1;          // 0..2047
    const int b  = stile >> 5;                  // 0..63
    const int s0 = (stile & 31) << 6;           // 0..1984

    // staging roles (A): 4 threads per row, 8 floats each
    const int arow = tid >> 2;      // 0..63
    const int akq  = tid & 3;       // k offset akq*8
    // compute roles
    const int lane = tid & 63;
    const int w    = tid >> 6;      // 0..3: hg-quad (64 h each)
    const int lrow = lane & 15;
    const int kblk = lane >> 4;     // 0..3

    f32x4 acc[4][4] = {};

    const float* ctx_src = ctx + ((size_t)b * S + s0 + arow) * D + akq * 8;
    // B global per-lane base for this wave's hg slices:
    const _Float16* Bg = WcP + ((size_t)(hb * 16 + w * 4) * 64 + lane) * 8;

    // ---- prologue: stage tile 0 into buf 0 ----
    #pragma unroll
    for (int i = 0; i < 4; ++i)
        GLOAD16(Bg + (size_t)(i * 64) * 8, &Blds[0][(w * 4 + i) * 512]);
    {
        float4 f0 = *(const float4*)ctx_src;
        float4 f1 = *(const float4*)(ctx_src + 4);
        union { fp16x2 h2[4]; f16x8 v; } u;
        u.h2[0] = __builtin_amdgcn_cvt_pkrtz(f0.x, f0.y);
        u.h2[1] = __builtin_amdgcn_cvt_pkrtz(f0.z, f0.w);
        u.h2[2] = __builtin_amdgcn_cvt_pkrtz(f1.x, f1.y);
        u.h2[3] = __builtin_amdgcn_cvt_pkrtz(f1.z, f1.w);
        *(f16x8*)&Alds[0][arow * LDA + akq * 8] = u.v;
    }
    __syncthreads();

    #pragma unroll 1
    for (int kt = 0; kt < 16; ++kt) {
        const int cur = kt & 1;

        // ---- issue next-tile staging into the other buffers (async) ----
        float4 nf0, nf1;
        if (kt < 15) {
            #pragma unroll
            for (int i = 0; i < 4; ++i)
                GLOAD16(Bg + ((size_t)(kt + 1) * 2048 + i * 64) * 8,
                        &Blds[cur ^ 1][(w * 4 + i) * 512]);
            nf0 = *(const float4*)(ctx_src + (kt + 1) * 32);
            nf1 = *(const float4*)(ctx_src + (kt + 1) * 32 + 4);
        }

        // ---- compute tile kt from LDS ----
        f16x8 bfr[4];
        #pragma unroll
        for (int n = 0; n < 4; ++n)
            bfr[n] = *(const f16x8*)&Blds[cur][(w * 4 + n) * 512 + lane * 8];
        f16x8 afr[4];
        #pragma unroll
        for (int m = 0; m < 4; ++m)
            afr[m] = *(const f16x8*)&Alds[cur][(m * 16 + lrow) * LDA + kblk * 8];

        #pragma unroll
        for (int m = 0; m < 4; ++m)
            #pragma unroll
            for (int n = 0; n < 4; ++n)
                acc[m][n] = __builtin_amdgcn_mfma_f32_16x16x32_f16(
                    afr[m], bfr[n], acc[m][n], 0, 0, 0);

        // ---- write next A tile ----
        if (kt < 15) {
            union { fp16x2 h2[4]; f16x8 v; } u;
            u.h2[0] = __builtin_amdgcn_cvt_pkrtz(nf0.x, nf0.y);
            u.h2[1] = __builtin_amdgcn_cvt_pkrtz(nf0.z, nf0.w);
            u.h2[2] = __builtin_amdgcn_cvt_pkrtz(nf1.x, nf1.y);
            u.h2[3] = __builtin_amdgcn_cvt_pkrtz(nf1.z, nf1.w);
            *(f16x8*)&Alds[cur ^ 1][arow * LDA + akq * 8] = u.v;
        }
        __syncthreads();   // drains gloads (vmcnt) + orders LDS for kt+1
    }

    // ---- epilogue: tanh + V weighting; reduce over this wave's 64 h ----
    float ps_[4][4] = {};   // [m][reg]
    #pragma unroll
    for (int n = 0; n < 4; ++n) {
        const int h = hb * 256 + (w * 4 + n) * 16 + lrow;
        const float ib = inp[(size_t)b * H + h] + bc[h];
        const float v = V[h];
        #pragma unroll
        for (int m = 0; m < 4; ++m)
            #pragma unroll
            for (int r = 0; r < 4; ++r) {
                const float x = acc[m][n][r] + ib;
                const float t = 1.f - 2.f / (1.f + __expf(2.f * x));
                ps_[m][r] += v * t;
            }
    }
    #pragma unroll
    for (int off = 1; off < 16; off <<= 1)
        #pragma unroll
        for (int m = 0; m < 4; ++m)
            #pragma unroll
            for (int r = 0; r < 4; ++r)
                ps_[m][r] += __shfl_xor(ps_[m][r], off, 64);
    if (lrow == 0) {
        #pragma unroll
        for (int m = 0; m < 4; ++m)
            #pragma unroll
            for (int r = 0; r < 4; ++r)
                red[w][m * 16 + kblk * 4 + r] = ps_[m][r];
    }
    __syncthreads();
    if (tid < 64) {
        const float sum = red[0][tid] + red[1][tid] + red[2][tid] + red[3][tid];
        atomicAdd(att + (size_t)b * S + s0 + tid, sum);
    }
}

// ---------------------------------------------------------------------------
// K4: mask branch + softmax per row (in place in the alpha region).
// ---------------------------------------------------------------------------
__global__ __launch_bounds__(256) void k_softmax(
        const int* __restrict__ mask,
        const float* __restrict__ amask,
        const int* __restrict__ cntArr,
        float* __restrict__ att) {
    const int b = blockIdx.x;
    const int tid = threadIdx.x;
    __shared__ float sh[S];
    __shared__ float fredm[4];
    __shared__ float freds[4];

    int n_true = 0;
    #pragma unroll
    for (int i = 0; i < 64; ++i) n_true += cntArr[i];
    const bool inf_branch = (n_true > 0) && (n_true == S);

    const float NEG_INF = -__builtin_inff();
    for (int s = tid; s < S; s += 256) {
        const float raw = att[(size_t)b * S + s];
        float v;
        if (inf_branch)
            v = mask[(size_t)b * S + s] ? NEG_INF : raw;
        else
            v = raw * amask[(size_t)b * S + s];
        sh[s] = v;
    }
    __syncthreads();

    float mx = NEG_INF;
    for (int s = tid; s < S; s += 256) mx = fmaxf(mx, sh[s]);
    #pragma unroll
    for (int off = 32; off; off >>= 1) mx = fmaxf(mx, __shfl_down(mx, off, 64));
    if ((tid & 63) == 0) fredm[tid >> 6] = mx;
    __syncthreads();
    mx = fmaxf(fmaxf(fredm[0], fredm[1]), fmaxf(fredm[2], fredm[3]));

    float lsum = 0.f;
    for (int s = tid; s < S; s += 256) {
        const float e = expf(sh[s] - mx);
        sh[s] = e;
        lsum += e;
    }
    #pragma unroll
    for (int off = 32; off; off >>= 1) lsum += __shfl_down(lsum, off, 64);
    if ((tid & 63) == 0) freds[tid >> 6] = lsum;
    __syncthreads();
    const float total = freds[0] + freds[1] + freds[2] + freds[3];
    const float rinv = 1.f / total;

    for (int s = tid; s < S; s += 256)
        att[(size_t)b * S + s] = sh[s] * rinv;
}

// ---------------------------------------------------------------------------
// K5: part[chunk][b][:] = sum_{s in chunk} alpha[b,s] * ctx[b,s,:]
// ---------------------------------------------------------------------------
__global__ __launch_bounds__(256) void k_wsum(
        const float* __restrict__ ctx,
        const float* __restrict__ alpha,
        float* __restrict__ part) {
    const int chunk = blockIdx.x & 15;
    const int b = blockIdx.x >> 4;
    const int s0 = chunk * WSC;
    const int tid = threadIdx.x;
    __shared__ float al[WSC];
    if (tid < WSC) al[tid] = alpha[(size_t)b * S + s0 + tid];
    __syncthreads();

    const int half = tid >> 7;
    const int dq = (tid & 127) * 4;
    const float* base = ctx + ((size_t)b * S + s0 + half) * D + dq;
    float4 acc = {0.f, 0.f, 0.f, 0.f};
    #pragma unroll 4
    for (int i = 0; i < WSC / 2; ++i) {
        float4 v = *(const float4*)(base + (size_t)i * 2 * D);
        const float a = al[i * 2 + half];
        acc.x += a * v.x; acc.y += a * v.y; acc.z += a * v.z; acc.w += a * v.w;
    }
    __shared__ float cb[2][D];
    *(float4*)&cb[half][dq] = acc;
    __syncthreads();
    if (tid < 128) {
        const int d = tid * 4;
        float4 p0 = *(const float4*)&cb[0][d];
        float4 p1 = *(const float4*)&cb[1][d];
        float4 o = {p0.x + p1.x, p0.y + p1.y, p0.z + p1.z, p0.w + p1.w};
        *(float4*)(part + ((size_t)chunk * B + b) * D + d) = o;
    }
}

// ---------------------------------------------------------------------------
// K6: hidden = Wc @ (sum of partials) + bc   (tiny GEMV per batch)
// ---------------------------------------------------------------------------
__global__ __launch_bounds__(256) void k_out(
        const float* __restrict__ part,
        const float* __restrict__ Wc,
        const float* __restrict__ bc,
        float* __restrict__ hidden) {
    const int b = blockIdx.x;
    const int tid = threadIdx.x;
    __shared__ float cb[D];
    for (int d = tid; d < D; d += 256) {
        float s = 0.f;
        #pragma unroll
        for (int c = 0; c < 16; ++c)
            s += part[((size_t)c * B + b) * D + d];
        cb[d] = s;
    }
    __syncthreads();
    for (int h = tid; h < H; h += 256) {
        const float* w = Wc + (size_t)h * D;
        float acc = 0.f;
        #pragma unroll 4
        for (int d = 0; d < D; d += 4) {
            float4 wv = *(const float4*)(w + d);
            acc += wv.x * cb[d] + wv.y * cb[d + 1] + wv.z * cb[d + 2] + wv.w * cb[d + 3];
        }
        hidden[(size_t)b * H + h] = acc + bc[h];
    }
}

// ---------------------------------------------------------------------------
extern "C" void kernel_launch(void* const* d_in, const int* in_sizes, int n_in,
                              void* d_out, int out_size, void* d_ws, size_t ws_size,
                              hipStream_t stream) {
    const float* input = (const float*)d_in[0];
    const float* ctx   = (const float*)d_in[1];
    const float* amask = (const float*)d_in[2];
    const float* W_in  = (const float*)d_in[3];
    const float* b_in  = (const float*)d_in[4];
    const float* W_ctx = (const float*)d_in[5];
    const float* b_ctx = (const float*)d_in[6];
    const float* V     = (const float*)d_in[7];
    const int*   mask  = (const int*)d_in[8];

    float* out = (float*)d_out;
    float* hidden = out;            // [B,H]
    float* alpha  = out + B * H;    // [B,S]

    _Float16* wsB    = (_Float16*)d_ws;
    float*    part   = (float*)((char*)d_ws + WS_PART_OFF);
    int*      cntArr = (int*)((char*)d_ws + WS_CNT_OFF);

    // K_prep: pack Wc + input linear (-> hidden region) + mask partial counts
    k_prep<<<dim3(256), dim3(256), 0, stream>>>(
        W_ctx, wsB, input, W_in, b_in, hidden, mask, cntArr);

    // K2: fused energy GEMM -> att (alpha region, atomic over h-halves)
    (void)hipMemsetAsync(alpha, 0, (size_t)B * S * sizeof(float), stream);
    k_energy<<<dim3(B * S / 64 * 2), dim3(256), 0, stream>>>(
        ctx, wsB, b_ctx, hidden, V, alpha);

    // K4: mask branch + softmax in place -> alpha final
    k_softmax<<<dim3(B), dim3(256), 0, stream>>>(mask, amask, cntArr, alpha);

    // K5: weighted context partial sums -> part
    k_wsum<<<dim3(16 * B), dim3(256), 0, stream>>>(ctx, alpha, part);

    // K6: hidden = Wc @ sum(part) + bc
    k_out<<<dim3(B), dim3(256), 0, stream>>>(part, W_ctx, b_ctx, hidden);
}

// Round 18
// 248.695 us; speedup vs baseline: 1.0128x; 1.0128x over previous
//
#include <hip/hip_runtime.h>
#include <math.h>

#define B 64
#define S 2048
#define D 512
#define H 512

#define WSC 128  // s-rows per k_wsum chunk

typedef _Float16 f16x8 __attribute__((ext_vector_type(8)));
typedef __fp16 fp16x2 __attribute__((ext_vector_type(2)));
typedef float f32x4 __attribute__((ext_vector_type(4)));

// ws layout: [0,512K) WcP packed fp16; [512K,512K+2M) wsum partials f32 [16][B][D];
//            [512K+4M, +256B) mask partial counts int[64]
#define WS_PART_OFF (512 * 1024)
#define WS_CNT_OFF  (512 * 1024 + 4 * 1024 * 1024)

// m104/m108: LDS dest = WAVE-UNIFORM base; HW writes lane l at base + l*16.
// Global src is per-lane (rule #21: linear dest + inverse-swizzled source).
#define GLOAD16(g, l)                                                          \
    __builtin_amdgcn_global_load_lds(                                          \
        (const __attribute__((address_space(1))) uint32_t*)(g),                \
        (__attribute__((address_space(3))) uint32_t*)(l), 16, 0, 0)

// ---------------------------------------------------------------------------
// K_prep: fused {pack Wc -> fp16 frag order} + {input linear} + {mask counts}
// ---------------------------------------------------------------------------
__global__ __launch_bounds__(256) void k_prep(
        const float* __restrict__ Wc, _Float16* __restrict__ wsB,
        const float* __restrict__ input, const float* __restrict__ W_in,
        const float* __restrict__ b_in, float* __restrict__ out_inp,
        const int* __restrict__ mask, int* __restrict__ cntArr) {
    const int bid = blockIdx.x;
    const int tid = threadIdx.x;

    if (bid < 128) {
        const int slot = bid * 256 + tid;   // 0..32767
        const int st   = slot >> 11;
        const int rem  = slot & 2047;
        const int hg   = rem >> 6;
        const int lane = rem & 63;
        const int h  = hg * 16 + (lane & 15);
        const int k0 = st * 32 + (lane >> 4) * 8;
        const float* src = Wc + (size_t)h * D + k0;
        float4 f0 = *(const float4*)src;
        float4 f1 = *(const float4*)(src + 4);
        f16x8 v;
        v[0] = (_Float16)f0.x; v[1] = (_Float16)f0.y;
        v[2] = (_Float16)f0.z; v[3] = (_Float16)f0.w;
        v[4] = (_Float16)f1.x; v[5] = (_Float16)f1.y;
        v[6] = (_Float16)f1.z; v[7] = (_Float16)f1.w;
        *(f16x8*)(wsB + (size_t)slot * 8) = v;
    } else if (bid < 192) {
        const int b = bid - 128;
        __shared__ float xrow[D];
        for (int d = tid; d < D; d += 256) xrow[d] = input[(size_t)b * D + d];
        __syncthreads();
        for (int h = tid; h < H; h += 256) {
            const float* w = W_in + (size_t)h * D;
            float acc = 0.f;
            #pragma unroll 4
            for (int d = 0; d < D; d += 4) {
                float4 wv = *(const float4*)(w + d);
                acc += wv.x * xrow[d] + wv.y * xrow[d + 1] + wv.z * xrow[d + 2] + wv.w * xrow[d + 3];
            }
            out_inp[(size_t)b * H + h] = acc + b_in[h];
        }
    } else {
        const int i0 = (bid - 192) * 2048;
        int local = 0;
        #pragma unroll
        for (int it = 0; it < 8; ++it)
            local += (mask[i0 + it * 256 + tid] != 0) ? 1 : 0;
        #pragma unroll
        for (int off = 32; off; off >>= 1) local += __shfl_down(local, off, 64);
        __shared__ int ired[4];
        if ((tid & 63) == 0) ired[tid >> 6] = local;
        __syncthreads();
        if (tid == 0) cntArr[bid - 192] = ired[0] + ired[1] + ired[2] + ired[3];
    }
}

// ---------------------------------------------------------------------------
// K2 (MFMA): fused ctx-GEMM + tanh + V-reduce. 4-DEEP A-CHUNK PIPELINE.
//   Block: 64 s-rows x full H=512, 8 waves (512 thr), wave 64s x 64h.
//   A staged as FP32 in 2 x 32KB LDS chunks (64 rows x 128 k) via
//   global_load_lds with inverse-swizzled global source (rule #21); the
//   fp32->fp16 cvt happens at fragment-read. ONE barrier per chunk
//   (4 K-steps): loads issued ~1280 cyc before their drain >= 900 cyc HBM
//   latency. B frags direct from packed-Wc L2 inside the barrier-free
//   4-step region (compiler free to pipeline).
// ---------------------------------------------------------------------------
__global__ __launch_bounds__(512, 4) void k_energy(
        const float* __restrict__ ctx,
        const _Float16* __restrict__ WcP,
        const float* __restrict__ bc,
        const float* __restrict__ inp,
        const float* __restrict__ V,
        float* __restrict__ att) {
    __shared__ alignas(16) float Af[2][64 * 128];   // 2 x 32 KB
    __shared__ float red[8][64];

    const int tid = threadIdx.x;
    const int b  = blockIdx.x >> 5;             // 0..63
    const int s0 = (blockIdx.x & 31) << 6;      // 0..1984

    const int lane = tid & 63;
    const int w    = tid >> 6;      // 0..7: h-slice (64 h each) + staging rows w*8..w*8+7
    const int lrow = lane & 15;
    const int kblk = lane >> 4;     // 0..3
    const int sw   = (lrow & 7) << 2;   // read-side slot swizzle

    f32x4 acc[4][4] = {};

    const _Float16* Bbase = WcP + ((size_t)(w * 4) * 64 + lane) * 8;

    // staging: wave w stages rows w*8..w*8+7; gload gi covers rows w*8+gi*2 +{0,1}
    // per-lane: row = w*8 + gi*2 + (lane>>5); logical slot g = (lane&31) ^ ((row&7)<<2)
    #define STAGE_CHUNK(BUF, CK)                                               \
        _Pragma("unroll")                                                      \
        for (int gi = 0; gi < 4; ++gi) {                                       \
            const int row_ = w * 8 + gi * 2 + (lane >> 5);                     \
            const int g_ = (lane & 31) ^ ((row_ & 7) << 2);                    \
            GLOAD16(ctx + ((size_t)b * S + s0 + row_) * D + (CK) * 128 + g_ * 4, \
                    &Af[BUF][(w * 8 + gi * 2) * 128]);                         \
        }

    // ---- prologue: stage chunk 0 ----
    STAGE_CHUNK(0, 0)
    __syncthreads();

    #pragma unroll 1
    for (int c = 0; c < 4; ++c) {
        const int cur = c & 1;

        // issue next chunk's async loads (drained at this chunk's end barrier)
        if (c < 3) STAGE_CHUNK(cur ^ 1, c + 1)

        // ---- 4 barrier-free K-steps from chunk c ----
        #pragma unroll
        for (int st = 0; st < 4; ++st) {
            const int stg = c * 4 + st;
            f16x8 bfr[4];
            #pragma unroll
            for (int n = 0; n < 4; ++n)
                bfr[n] = *(const f16x8*)(Bbase + ((size_t)stg * 2048 + n * 64) * 8);

            f16x8 afr[4];
            #pragma unroll
            for (int m = 0; m < 4; ++m) {
                const int ph0 = (st * 8 + kblk * 2) ^ sw;
                const int ph1 = (st * 8 + kblk * 2 + 1) ^ sw;
                const float* rb = &Af[cur][(m * 16 + lrow) * 128];
                float4 f0 = *(const float4*)(rb + ph0 * 4);
                float4 f1 = *(const float4*)(rb + ph1 * 4);
                union { fp16x2 h2[4]; f16x8 v; } u;
                u.h2[0] = __builtin_amdgcn_cvt_pkrtz(f0.x, f0.y);
                u.h2[1] = __builtin_amdgcn_cvt_pkrtz(f0.z, f0.w);
                u.h2[2] = __builtin_amdgcn_cvt_pkrtz(f1.x, f1.y);
                u.h2[3] = __builtin_amdgcn_cvt_pkrtz(f1.z, f1.w);
                afr[m] = u.v;
            }

            #pragma unroll
            for (int m = 0; m < 4; ++m)
                #pragma unroll
                for (int n = 0; n < 4; ++n)
                    acc[m][n] = __builtin_amdgcn_mfma_f32_16x16x32_f16(
                        afr[m], bfr[n], acc[m][n], 0, 0, 0);
        }

        __syncthreads();   // drains next-chunk gloads; swap buffers
    }
    #undef STAGE_CHUNK

    // ---- epilogue: tanh + V weighting; reduce over this wave's 64 h ----
    float ps_[4][4] = {};   // [m][reg]
    #pragma unroll
    for (int n = 0; n < 4; ++n) {
        const int h = w * 64 + n * 16 + lrow;
        const float ib = inp[(size_t)b * H + h] + bc[h];
        const float v = V[h];
        #pragma unroll
        for (int m = 0; m < 4; ++m)
            #pragma unroll
            for (int r = 0; r < 4; ++r) {
                const float x = acc[m][n][r] + ib;
                const float t = 1.f - 2.f / (1.f + __expf(2.f * x));
                ps_[m][r] += v * t;
            }
    }
    #pragma unroll
    for (int off = 1; off < 16; off <<= 1)
        #pragma unroll
        for (int m = 0; m < 4; ++m)
            #pragma unroll
            for (int r = 0; r < 4; ++r)
                ps_[m][r] += __shfl_xor(ps_[m][r], off, 64);
    if (lrow == 0) {
        #pragma unroll
        for (int m = 0; m < 4; ++m)
            #pragma unroll
            for (int r = 0; r < 4; ++r)
                red[w][m * 16 + kblk * 4 + r] = ps_[m][r];
    }
    __syncthreads();
    if (tid < 64) {
        float sum = 0.f;
        #pragma unroll
        for (int i = 0; i < 8; ++i) sum += red[i][tid];
        att[(size_t)b * S + s0 + tid] = sum;
    }
}

// ---------------------------------------------------------------------------
// K4: mask branch + softmax per row (in place in the alpha region).
// ---------------------------------------------------------------------------
__global__ __launch_bounds__(256) void k_softmax(
        const int* __restrict__ mask,
        const float* __restrict__ amask,
        const int* __restrict__ cntArr,
        float* __restrict__ att) {
    const int b = blockIdx.x;
    const int tid = threadIdx.x;
    __shared__ float sh[S];
    __shared__ float fredm[4];
    __shared__ float freds[4];

    int n_true = 0;
    #pragma unroll
    for (int i = 0; i < 64; ++i) n_true += cntArr[i];
    const bool inf_branch = (n_true > 0) && (n_true == S);

    const float NEG_INF = -__builtin_inff();
    for (int s = tid; s < S; s += 256) {
        const float raw = att[(size_t)b * S + s];
        float v;
        if (inf_branch)
            v = mask[(size_t)b * S + s] ? NEG_INF : raw;
        else
            v = raw * amask[(size_t)b * S + s];
        sh[s] = v;
    }
    __syncthreads();

    float mx = NEG_INF;
    for (int s = tid; s < S; s += 256) mx = fmaxf(mx, sh[s]);
    #pragma unroll
    for (int off = 32; off; off >>= 1) mx = fmaxf(mx, __shfl_down(mx, off, 64));
    if ((tid & 63) == 0) fredm[tid >> 6] = mx;
    __syncthreads();
    mx = fmaxf(fmaxf(fredm[0], fredm[1]), fmaxf(fredm[2], fredm[3]));

    float lsum = 0.f;
    for (int s = tid; s < S; s += 256) {
        const float e = expf(sh[s] - mx);
        sh[s] = e;
        lsum += e;
    }
    #pragma unroll
    for (int off = 32; off; off >>= 1) lsum += __shfl_down(lsum, off, 64);
    if ((tid & 63) == 0) freds[tid >> 6] = lsum;
    __syncthreads();
    const float total = freds[0] + freds[1] + freds[2] + freds[3];
    const float rinv = 1.f / total;

    for (int s = tid; s < S; s += 256)
        att[(size_t)b * S + s] = sh[s] * rinv;
}

// ---------------------------------------------------------------------------
// K5: part[chunk][b][:] = sum_{s in chunk} alpha[b,s] * ctx[b,s,:]
// ---------------------------------------------------------------------------
__global__ __launch_bounds__(256) void k_wsum(
        const float* __restrict__ ctx,
        const float* __restrict__ alpha,
        float* __restrict__ part) {
    const int chunk = blockIdx.x & 15;
    const int b = blockIdx.x >> 4;
    const int s0 = chunk * WSC;
    const int tid = threadIdx.x;
    __shared__ float al[WSC];
    if (tid < WSC) al[tid] = alpha[(size_t)b * S + s0 + tid];
    __syncthreads();

    const int half = tid >> 7;
    const int dq = (tid & 127) * 4;
    const float* base = ctx + ((size_t)b * S + s0 + half) * D + dq;
    float4 acc = {0.f, 0.f, 0.f, 0.f};
    #pragma unroll 4
    for (int i = 0; i < WSC / 2; ++i) {
        float4 v = *(const float4*)(base + (size_t)i * 2 * D);
        const float a = al[i * 2 + half];
        acc.x += a * v.x; acc.y += a * v.y; acc.z += a * v.z; acc.w += a * v.w;
    }
    __shared__ float cb[2][D];
    *(float4*)&cb[half][dq] = acc;
    __syncthreads();
    if (tid < 128) {
        const int d = tid * 4;
        float4 p0 = *(const float4*)&cb[0][d];
        float4 p1 = *(const float4*)&cb[1][d];
        float4 o = {p0.x + p1.x, p0.y + p1.y, p0.z + p1.z, p0.w + p1.w};
        *(float4*)(part + ((size_t)chunk * B + b) * D + d) = o;
    }
}

// ---------------------------------------------------------------------------
// K6: hidden = Wc @ (sum of partials) + bc   (tiny GEMV per batch)
// ---------------------------------------------------------------------------
__global__ __launch_bounds__(256) void k_out(
        const float* __restrict__ part,
        const float* __restrict__ Wc,
        const float* __restrict__ bc,
        float* __restrict__ hidden) {
    const int b = blockIdx.x;
    const int tid = threadIdx.x;
    __shared__ float cb[D];
    for (int d = tid; d < D; d += 256) {
        float s = 0.f;
        #pragma unroll
        for (int c = 0; c < 16; ++c)
            s += part[((size_t)c * B + b) * D + d];
        cb[d] = s;
    }
    __syncthreads();
    for (int h = tid; h < H; h += 256) {
        const float* w = Wc + (size_t)h * D;
        float acc = 0.f;
        #pragma unroll 4
        for (int d = 0; d < D; d += 4) {
            float4 wv = *(const float4*)(w + d);
            acc += wv.x * cb[d] + wv.y * cb[d + 1] + wv.z * cb[d + 2] + wv.w * cb[d + 3];
        }
        hidden[(size_t)b * H + h] = acc + bc[h];
    }
}

// ---------------------------------------------------------------------------
extern "C" void kernel_launch(void* const* d_in, const int* in_sizes, int n_in,
                              void* d_out, int out_size, void* d_ws, size_t ws_size,
                              hipStream_t stream) {
    const float* input = (const float*)d_in[0];
    const float* ctx   = (const float*)d_in[1];
    const float* amask = (const float*)d_in[2];
    const float* W_in  = (const float*)d_in[3];
    const float* b_in  = (const float*)d_in[4];
    const float* W_ctx = (const float*)d_in[5];
    const float* b_ctx = (const float*)d_in[6];
    const float* V     = (const float*)d_in[7];
    const int*   mask  = (const int*)d_in[8];

    float* out = (float*)d_out;
    float* hidden = out;            // [B,H]
    float* alpha  = out + B * H;    // [B,S]

    _Float16* wsB    = (_Float16*)d_ws;
    float*    part   = (float*)((char*)d_ws + WS_PART_OFF);
    int*      cntArr = (int*)((char*)d_ws + WS_CNT_OFF);

    // K_prep: pack Wc + input linear (-> hidden region) + mask partial counts
    k_prep<<<dim3(256), dim3(256), 0, stream>>>(
        W_ctx, wsB, input, W_in, b_in, hidden, mask, cntArr);

    // K2: fused energy GEMM -> att (alpha region, direct store)
    k_energy<<<dim3(B * S / 64), dim3(512), 0, stream>>>(
        ctx, wsB, b_ctx, hidden, V, alpha);

    // K4: mask branch + softmax in place -> alpha final
    k_softmax<<<dim3(B), dim3(256), 0, stream>>>(mask, amask, cntArr, alpha);

    // K5: weighted context partial sums -> part
    k_wsum<<<dim3(16 * B), dim3(256), 0, stream>>>(ctx, alpha, part);

    // K6: hidden = Wc @ sum(part) + bc
    k_out<<<dim3(B), dim3(256), 0, stream>>>(part, W_ctx, b_ctx, hidden);
}

// Round 19
// 227.984 us; speedup vs baseline: 1.1048x; 1.0908x over previous
//
#include <hip/hip_runtime.h>
#include <math.h>

#define B 64
#define S 2048
#define D 512
#define H 512

#define BK 64    // k per barrier interval (2 MFMA sub-phases of 32)

typedef _Float16 f16x8 __attribute__((ext_vector_type(8)));
typedef __fp16 fp16x2 __attribute__((ext_vector_type(2)));
typedef float f32x4 __attribute__((ext_vector_type(4)));

// ws layout:
//   [0, 512K)          WcP packed fp16
//   [512K, 512K+4M)    wsum partials f32 [32][B][D]
//   [512K+4M, +256B)   mask partial counts int[64]
//   [8M, 8M+134.2M)    ctx16: fp16 swizzled A-tiles [2048 blocks][8 kt][64 row][64 halfs]
#define WS_PART_OFF  (512 * 1024)
#define WS_CNT_OFF   (512 * 1024 + 4 * 1024 * 1024)
#define WS_CTX16_OFF (8 * 1024 * 1024)

// ---------------------------------------------------------------------------
// K_prep: fused {pack Wc -> fp16 frag order} + {input linear} + {mask counts}
//   blocks 0..127   : pack (slot = bid*256+tid)
//   blocks 128..191 : inp = input @ W_in^T + b_in  (b = bid-128) -> hidden region
//   blocks 192..255 : per-block mask partial count -> cntArr[bid-192]
// ---------------------------------------------------------------------------
__global__ __launch_bounds__(256) void k_prep(
        const float* __restrict__ Wc, _Float16* __restrict__ wsB,
        const float* __restrict__ input, const float* __restrict__ W_in,
        const float* __restrict__ b_in, float* __restrict__ out_inp,
        const int* __restrict__ mask, int* __restrict__ cntArr) {
    const int bid = blockIdx.x;
    const int tid = threadIdx.x;

    if (bid < 128) {
        const int slot = bid * 256 + tid;   // 0..32767
        const int st   = slot >> 11;
        const int rem  = slot & 2047;
        const int hg   = rem >> 6;
        const int lane = rem & 63;
        const int h  = hg * 16 + (lane & 15);
        const int k0 = st * 32 + (lane >> 4) * 8;
        const float* src = Wc + (size_t)h * D + k0;
        float4 f0 = *(const float4*)src;
        float4 f1 = *(const float4*)(src + 4);
        f16x8 v;
        v[0] = (_Float16)f0.x; v[1] = (_Float16)f0.y;
        v[2] = (_Float16)f0.z; v[3] = (_Float16)f0.w;
        v[4] = (_Float16)f1.x; v[5] = (_Float16)f1.y;
        v[6] = (_Float16)f1.z; v[7] = (_Float16)f1.w;
        *(f16x8*)(wsB + (size_t)slot * 8) = v;
    } else if (bid < 192) {
        const int b = bid - 128;
        __shared__ float xrow[D];
        for (int d = tid; d < D; d += 256) xrow[d] = input[(size_t)b * D + d];
        __syncthreads();
        for (int h = tid; h < H; h += 256) {
            const float* w = W_in + (size_t)h * D;
            float acc = 0.f;
            #pragma unroll 4
            for (int d = 0; d < D; d += 4) {
                float4 wv = *(const float4*)(w + d);
                acc += wv.x * xrow[d] + wv.y * xrow[d + 1] + wv.z * xrow[d + 2] + wv.w * xrow[d + 3];
            }
            out_inp[(size_t)b * H + h] = acc + b_in[h];
        }
    } else {
        const int i0 = (bid - 192) * 2048;
        int local = 0;
        #pragma unroll
        for (int it = 0; it < 8; ++it)
            local += (mask[i0 + it * 256 + tid] != 0) ? 1 : 0;
        #pragma unroll
        for (int off = 32; off; off >>= 1) local += __shfl_down(local, off, 64);
        __shared__ int ired[4];
        if ((tid & 63) == 0) ired[tid >> 6] = local;
        __syncthreads();
        if (tid == 0) cntArr[bid - 192] = ired[0] + ired[1] + ired[2] + ired[3];
    }
}

// ---------------------------------------------------------------------------
// K2 (MFMA): fused ctx-GEMM + tanh + V-reduce (r13 structure) + fp16 A-tile
//   writeback to ws (consumed by k_wsum at half the HBM bytes).
// ---------------------------------------------------------------------------
__global__ __launch_bounds__(512, 4) void k_energy(
        const float* __restrict__ ctx,
        const _Float16* __restrict__ WcP,
        const float* __restrict__ bc,
        const float* __restrict__ inp,
        const float* __restrict__ V,
        float* __restrict__ att,
        _Float16* __restrict__ ctx16) {
    __shared__ alignas(16) _Float16 Alds[2][64 * BK];   // 2 x 8 KB
    __shared__ float red[8][64];

    const int tid = threadIdx.x;
    const int b  = blockIdx.x >> 5;             // 32 s-tiles per batch
    const int s0 = (blockIdx.x & 31) << 6;

    // staging roles: 8 threads per row, 8 floats (16 B fp16) each
    const int arow = tid >> 3;      // 0..63
    const int akq  = tid & 7;       // 0..7 -> slot before swizzle
    const int wslot = akq ^ (arow & 7);
    const int toff = arow * 64 + wslot * 8;     // shared LDS/ws tile offset
    // compute roles
    const int lane = tid & 63;
    const int w    = tid >> 6;      // 0..7: h-slice (64 h each)
    const int lrow = lane & 15;
    const int kblk = lane >> 4;     // 0..3

    f32x4 acc[4][4] = {};

    const float* ctx_src = ctx + ((size_t)b * S + s0 + arow) * D + akq * 8;
    const _Float16* Bbase = WcP + ((size_t)(w * 4) * 64 + lane) * 8;
    _Float16* wb = ctx16 + (size_t)blockIdx.x * 32768;
    const int rsw = lrow & 7;

    // ---- prologue: stage A(0) into buf 0 (+ writeback) ----
    {
        float4 f0 = *(const float4*)ctx_src;
        float4 f1 = *(const float4*)(ctx_src + 4);
        union { fp16x2 h2[4]; f16x8 v; } u;
        u.h2[0] = __builtin_amdgcn_cvt_pkrtz(f0.x, f0.y);
        u.h2[1] = __builtin_amdgcn_cvt_pkrtz(f0.z, f0.w);
        u.h2[2] = __builtin_amdgcn_cvt_pkrtz(f1.x, f1.y);
        u.h2[3] = __builtin_amdgcn_cvt_pkrtz(f1.z, f1.w);
        *(f16x8*)&Alds[0][toff] = u.v;
        *(f16x8*)(wb + toff) = u.v;
    }
    __syncthreads();

    #pragma unroll 1
    for (int kt = 0; kt < 8; ++kt) {
        const int cur = kt & 1;
        const _Float16* Ab = &Alds[cur][0];
        const size_t st0 = (size_t)(kt * 2) * 2048;
        const size_t st1 = (size_t)(kt * 2 + 1) * 2048;

        // ---- (a) B loads for sub-phase 0 ----
        f16x8 b00 = *(const f16x8*)(Bbase + (st0 + 0 * 64) * 8);
        f16x8 b01 = *(const f16x8*)(Bbase + (st0 + 1 * 64) * 8);
        f16x8 b02 = *(const f16x8*)(Bbase + (st0 + 2 * 64) * 8);
        f16x8 b03 = *(const f16x8*)(Bbase + (st0 + 3 * 64) * 8);
        __builtin_amdgcn_sched_barrier(0);

        // ---- (b) A frags sub0 from swizzled LDS ----
        const int sl0 = kblk ^ rsw;
        f16x8 a00 = *(const f16x8*)(Ab + (0 * 16 + lrow) * BK + sl0 * 8);
        f16x8 a01 = *(const f16x8*)(Ab + (1 * 16 + lrow) * BK + sl0 * 8);
        f16x8 a02 = *(const f16x8*)(Ab + (2 * 16 + lrow) * BK + sl0 * 8);
        f16x8 a03 = *(const f16x8*)(Ab + (3 * 16 + lrow) * BK + sl0 * 8);

        // ---- (c) B loads for sub-phase 1 (latency covered by MFMA sub0) ----
        f16x8 b10 = *(const f16x8*)(Bbase + (st1 + 0 * 64) * 8);
        f16x8 b11 = *(const f16x8*)(Bbase + (st1 + 1 * 64) * 8);
        f16x8 b12 = *(const f16x8*)(Bbase + (st1 + 2 * 64) * 8);
        f16x8 b13 = *(const f16x8*)(Bbase + (st1 + 3 * 64) * 8);

        // ---- (d) MFMA sub-phase 0 ----
        {
            f16x8 af_[4] = {a00, a01, a02, a03};
            f16x8 bf_[4] = {b00, b01, b02, b03};
            #pragma unroll
            for (int m = 0; m < 4; ++m)
                #pragma unroll
                for (int n = 0; n < 4; ++n)
                    acc[m][n] = __builtin_amdgcn_mfma_f32_16x16x32_f16(
                        af_[m], bf_[n], acc[m][n], 0, 0, 0);
        }

        // ---- (e) next A-tile global loads (covered by MFMA sub1 + barrier) ----
        float4 nf0, nf1;
        if (kt < 7) {
            nf0 = *(const float4*)(ctx_src + (kt + 1) * BK);
            nf1 = *(const float4*)(ctx_src + (kt + 1) * BK + 4);
        }

        // ---- (f) A frags sub1 ----
        const int sl1 = (4 + kblk) ^ rsw;
        f16x8 a10 = *(const f16x8*)(Ab + (0 * 16 + lrow) * BK + sl1 * 8);
        f16x8 a11 = *(const f16x8*)(Ab + (1 * 16 + lrow) * BK + sl1 * 8);
        f16x8 a12 = *(const f16x8*)(Ab + (2 * 16 + lrow) * BK + sl1 * 8);
        f16x8 a13 = *(const f16x8*)(Ab + (3 * 16 + lrow) * BK + sl1 * 8);
        __builtin_amdgcn_sched_barrier(0);

        // ---- (g) MFMA sub-phase 1 ----
        {
            f16x8 af_[4] = {a10, a11, a12, a13};
            f16x8 bf_[4] = {b10, b11, b12, b13};
            #pragma unroll
            for (int m = 0; m < 4; ++m)
                #pragma unroll
                for (int n = 0; n < 4; ++n)
                    acc[m][n] = __builtin_amdgcn_mfma_f32_16x16x32_f16(
                        af_[m], bf_[n], acc[m][n], 0, 0, 0);
        }
        __builtin_amdgcn_sched_barrier(0);

        // ---- (h) cvt + write next A tile to the other buffer (+ writeback) ----
        if (kt < 7) {
            union { fp16x2 h2[4]; f16x8 v; } u;
            u.h2[0] = __builtin_amdgcn_cvt_pkrtz(nf0.x, nf0.y);
            u.h2[1] = __builtin_amdgcn_cvt_pkrtz(nf0.z, nf0.w);
            u.h2[2] = __builtin_amdgcn_cvt_pkrtz(nf1.x, nf1.y);
            u.h2[3] = __builtin_amdgcn_cvt_pkrtz(nf1.z, nf1.w);
            *(f16x8*)&Alds[cur ^ 1][toff] = u.v;
            *(f16x8*)(wb + (size_t)(kt + 1) * 4096 + toff) = u.v;
        }
        __syncthreads();
    }

    // ---- epilogue: tanh + V weighting; reduce over this wave's 64 h ----
    float ps_[4][4] = {};   // [m][reg]
    #pragma unroll
    for (int n = 0; n < 4; ++n) {
        const int h = w * 64 + n * 16 + lrow;
        const float ib = inp[(size_t)b * H + h] + bc[h];
        const float v = V[h];
        #pragma unroll
        for (int m = 0; m < 4; ++m)
            #pragma unroll
            for (int r = 0; r < 4; ++r) {
                const float x = acc[m][n][r] + ib;
                const float t = 1.f - 2.f / (1.f + __expf(2.f * x));
                ps_[m][r] += v * t;
            }
    }
    #pragma unroll
    for (int off = 1; off < 16; off <<= 1)
        #pragma unroll
        for (int m = 0; m < 4; ++m)
            #pragma unroll
            for (int r = 0; r < 4; ++r)
                ps_[m][r] += __shfl_xor(ps_[m][r], off, 64);
    if (lrow == 0) {
        #pragma unroll
        for (int m = 0; m < 4; ++m)
            #pragma unroll
            for (int r = 0; r < 4; ++r)
                red[w][m * 16 + kblk * 4 + r] = ps_[m][r];
    }
    __syncthreads();
    if (tid < 64) {
        float sum = 0.f;
        #pragma unroll
        for (int i = 0; i < 8; ++i) sum += red[i][tid];
        att[(size_t)b * S + s0 + tid] = sum;
    }
}

// ---------------------------------------------------------------------------
// K4: mask branch + softmax per row (in place in the alpha region).
// ---------------------------------------------------------------------------
__global__ __launch_bounds__(256) void k_softmax(
        const int* __restrict__ mask,
        const float* __restrict__ amask,
        const int* __restrict__ cntArr,
        float* __restrict__ att) {
    const int b = blockIdx.x;
    const int tid = threadIdx.x;
    __shared__ float sh[S];
    __shared__ float fredm[4];
    __shared__ float freds[4];

    int n_true = 0;
    #pragma unroll
    for (int i = 0; i < 64; ++i) n_true += cntArr[i];
    const bool inf_branch = (n_true > 0) && (n_true == S);

    const float NEG_INF = -__builtin_inff();
    for (int s = tid; s < S; s += 256) {
        const float raw = att[(size_t)b * S + s];
        float v;
        if (inf_branch)
            v = mask[(size_t)b * S + s] ? NEG_INF : raw;
        else
            v = raw * amask[(size_t)b * S + s];
        sh[s] = v;
    }
    __syncthreads();

    float mx = NEG_INF;
    for (int s = tid; s < S; s += 256) mx = fmaxf(mx, sh[s]);
    #pragma unroll
    for (int off = 32; off; off >>= 1) mx = fmaxf(mx, __shfl_down(mx, off, 64));
    if ((tid & 63) == 0) fredm[tid >> 6] = mx;
    __syncthreads();
    mx = fmaxf(fmaxf(fredm[0], fredm[1]), fmaxf(fredm[2], fredm[3]));

    float lsum = 0.f;
    for (int s = tid; s < S; s += 256) {
        const float e = expf(sh[s] - mx);
        sh[s] = e;
        lsum += e;
    }
    #pragma unroll
    for (int off = 32; off; off >>= 1) lsum += __shfl_down(lsum, off, 64);
    if ((tid & 63) == 0) freds[tid >> 6] = lsum;
    __syncthreads();
    const float total = freds[0] + freds[1] + freds[2] + freds[3];
    const float rinv = 1.f / total;

    for (int s = tid; s < S; s += 256)
        att[(size_t)b * S + s] = sh[s] * rinv;
}

// ---------------------------------------------------------------------------
// K5: part[c][b][:] = sum_{s in chunk c} alpha[b,s] * ctx16-tile rows
//   Reads the fp16 swizzled tiles k_energy exported (half the HBM bytes).
//   Tile layout: [eb][kt][row][physslot*8], physslot = q ^ (row&7),
//   logical k = (kt*8 + q)*8 + j = ko*8 + j.
// ---------------------------------------------------------------------------
__global__ __launch_bounds__(256) void k_wsum(
        const _Float16* __restrict__ ctx16,
        const float* __restrict__ alpha,
        float* __restrict__ part) {
    const int eb = blockIdx.x;          // == b*32 + c, same decode as k_energy
    const int b = eb >> 5;
    const int c = eb & 31;
    const int s0 = c * 64;
    const int tid = threadIdx.x;
    const int ko = tid & 63;            // k-owner: kt = ko>>3, q = ko&7
    const int rg = tid >> 6;            // row-group 0..3 (16 rows each)

    __shared__ float al[64];
    if (tid < 64) al[tid] = alpha[(size_t)b * S + s0 + tid];
    __syncthreads();

    const _Float16* base = ctx16 + (size_t)eb * 32768 + (size_t)(ko >> 3) * 4096;
    const int q = ko & 7;

    float acc[8] = {};
    #pragma unroll 4
    for (int rr = 0; rr < 16; ++rr) {
        const int r = rg * 16 + rr;
        f16x8 v = *(const f16x8*)(base + r * 64 + (q ^ (r & 7)) * 8);
        const float a = al[r];
        #pragma unroll
        for (int j = 0; j < 8; ++j) acc[j] += a * (float)v[j];
    }

    __shared__ float red[4][512];
    #pragma unroll
    for (int j = 0; j < 8; ++j) red[rg][ko * 8 + j] = acc[j];
    __syncthreads();
    if (tid < 128) {
        const int d = tid * 4;
        float4 o;
        o.x = red[0][d + 0] + red[1][d + 0] + red[2][d + 0] + red[3][d + 0];
        o.y = red[0][d + 1] + red[1][d + 1] + red[2][d + 1] + red[3][d + 1];
        o.z = red[0][d + 2] + red[1][d + 2] + red[2][d + 2] + red[3][d + 2];
        o.w = red[0][d + 3] + red[1][d + 3] + red[2][d + 3] + red[3][d + 3];
        *(float4*)(part + ((size_t)c * B + b) * D + d) = o;
    }
}

// ---------------------------------------------------------------------------
// K6: hidden = Wc @ (sum of 32 partials) + bc   (tiny GEMV per batch)
// ---------------------------------------------------------------------------
__global__ __launch_bounds__(256) void k_out(
        const float* __restrict__ part,
        const float* __restrict__ Wc,
        const float* __restrict__ bc,
        float* __restrict__ hidden) {
    const int b = blockIdx.x;
    const int tid = threadIdx.x;
    __shared__ float cb[D];
    for (int d = tid; d < D; d += 256) {
        float s = 0.f;
        #pragma unroll
        for (int c = 0; c < 32; ++c)
            s += part[((size_t)c * B + b) * D + d];
        cb[d] = s;
    }
    __syncthreads();
    for (int h = tid; h < H; h += 256) {
        const float* w = Wc + (size_t)h * D;
        float acc = 0.f;
        #pragma unroll 4
        for (int d = 0; d < D; d += 4) {
            float4 wv = *(const float4*)(w + d);
            acc += wv.x * cb[d] + wv.y * cb[d + 1] + wv.z * cb[d + 2] + wv.w * cb[d + 3];
        }
        hidden[(size_t)b * H + h] = acc + bc[h];
    }
}

// ---------------------------------------------------------------------------
extern "C" void kernel_launch(void* const* d_in, const int* in_sizes, int n_in,
                              void* d_out, int out_size, void* d_ws, size_t ws_size,
                              hipStream_t stream) {
    const float* input = (const float*)d_in[0];
    const float* ctx   = (const float*)d_in[1];
    const float* amask = (const float*)d_in[2];
    const float* W_in  = (const float*)d_in[3];
    const float* b_in  = (const float*)d_in[4];
    const float* W_ctx = (const float*)d_in[5];
    const float* b_ctx = (const float*)d_in[6];
    const float* V     = (const float*)d_in[7];
    const int*   mask  = (const int*)d_in[8];

    float* out = (float*)d_out;
    float* hidden = out;            // [B,H]
    float* alpha  = out + B * H;    // [B,S]

    _Float16* wsB    = (_Float16*)d_ws;
    float*    part   = (float*)((char*)d_ws + WS_PART_OFF);
    int*      cntArr = (int*)((char*)d_ws + WS_CNT_OFF);
    _Float16* ctx16  = (_Float16*)((char*)d_ws + WS_CTX16_OFF);

    // K_prep: pack Wc + input linear (-> hidden region) + mask partial counts
    k_prep<<<dim3(256), dim3(256), 0, stream>>>(
        W_ctx, wsB, input, W_in, b_in, hidden, mask, cntArr);

    // K2: fused energy GEMM -> att (alpha region) + fp16 ctx tiles -> ws
    k_energy<<<dim3(B * S / 64), dim3(512), 0, stream>>>(
        ctx, wsB, b_ctx, hidden, V, alpha, ctx16);

    // K4: mask branch + softmax in place -> alpha final
    k_softmax<<<dim3(B), dim3(256), 0, stream>>>(mask, amask, cntArr, alpha);

    // K5: weighted context partial sums from fp16 tiles -> part
    k_wsum<<<dim3(B * 32), dim3(256), 0, stream>>>(ctx16, alpha, part);

    // K6: hidden = Wc @ sum(part) + bc
    k_out<<<dim3(B), dim3(256), 0, stream>>>(part, W_ctx, b_ctx, hidden);
}